// Round 7
// baseline (603.281 us; speedup 1.0000x reference)
//
#include <hip/hip_runtime.h>

#define SS 4096
#define NROWS 16384   // B*S

typedef __bf16 bf16;
typedef __attribute__((ext_vector_type(8))) __bf16 bf16x8;
typedef __attribute__((ext_vector_type(4))) float f32x4;

__device__ __forceinline__ float b2f(bf16 v) { return (float)v; }
__device__ __forceinline__ bf16  f2b(float f) { return (bf16)f; }

// ---------------------------------------------------------------- prep
__global__ __launch_bounds__(256) void prep_kernel(
    const float* __restrict__ x, float* __restrict__ pos,
    bf16* __restrict__ featb, float* __restrict__ sq)
{
    int row = blockIdx.x, t = threadIdx.x;
    const float* xr = x + (size_t)row * 259;
    float v = xr[3 + t];
    featb[(size_t)row * 256 + t] = f2b(v);
    if (t < 3) pos[row * 3 + t] = xr[t];
    float s = v * v;
#pragma unroll
    for (int o = 32; o >= 1; o >>= 1) s += __shfl_xor(s, o);
    __shared__ float wsum[4];
    if ((t & 63) == 0) wsum[t >> 6] = s;
    __syncthreads();
    if (t == 0) sq[row] = wsum[0] + wsum[1] + wsum[2] + wsum[3];
}

// ---------------------------------------------------------------- weight prep, stage 1
__global__ void wprep1_kernel(const float* __restrict__ wqw, const float* __restrict__ wkw,
                              const float* __restrict__ g1w, const float* __restrict__ fc2w,
                              const float* __restrict__ g2w,
                              float* __restrict__ M1q, float* __restrict__ M1k,
                              bf16* __restrict__ fc2T, bf16* __restrict__ g2T)
{
    int job = blockIdx.y, i = blockIdx.x, j = threadIdx.x;
    if (job < 2) {
        const float* A = job ? wkw : wqw;
        float acc = 0.f;
#pragma unroll 4
        for (int d = 0; d < 256; d++) acc += A[i * 256 + d] * g1w[d * 256 + j];
        (job ? M1k : M1q)[i * 256 + j] = acc;
    } else {
        const float* S = (job == 2) ? fc2w : g2w;
        bf16* D = (job == 2) ? fc2T : g2T;
        D[i * 256 + j] = f2b(S[j * 256 + i]);
    }
}

// ---------------------------------------------------------------- weight prep, stage 2
__global__ void wprep2_kernel(const float* __restrict__ fc1w, const float* __restrict__ fc1b,
                              const float* __restrict__ M1q, const float* __restrict__ M1k,
                              const float* __restrict__ wvw, const float* __restrict__ g1b,
                              bf16* __restrict__ WqT, bf16* __restrict__ WkT, bf16* __restrict__ WvT,
                              float* __restrict__ qbias, float* __restrict__ kbias, float* __restrict__ vbias)
{
    int job = blockIdx.y, n = blockIdx.x, k = threadIdx.x;
    if (job < 3) {
        const float* M = (job == 0) ? M1q : (job == 1) ? M1k : wvw;
        float acc = 0.f;
#pragma unroll 4
        for (int d = 0; d < 256; d++) acc += fc1w[k * 256 + d] * M[d * 256 + n];
        bf16* D = (job == 0) ? WqT : (job == 1) ? WkT : WvT;
        D[n * 256 + k] = f2b(acc);
    } else if (n == 0) {
        float aq = 0.f, ak = 0.f, av = 0.f;
#pragma unroll 4
        for (int d = 0; d < 256; d++) {
            float f = fc1b[d];
            aq += f * M1q[d * 256 + k];
            ak += f * M1k[d * 256 + k];
            av += f * wvw[d * 256 + k];
        }
        qbias[k] = aq + g1b[k];
        kbias[k] = ak;
        vbias[k] = av;
    }
}

// ---------------------------------------------------------------- q/k/v GEMM (one launch, z-indexed)
__global__ __launch_bounds__(256, 3) void qkv_gemm_kernel(
    const bf16* __restrict__ A,
    const bf16* __restrict__ BT0, const bf16* __restrict__ BT1, const bf16* __restrict__ BT2,
    const float* __restrict__ bias0, const float* __restrict__ bias1, const float* __restrict__ bias2,
    bf16* __restrict__ O0, bf16* __restrict__ O1, bf16* __restrict__ O2)
{
    int z = blockIdx.z;
    const bf16* BT = (z == 0) ? BT0 : (z == 1) ? BT1 : BT2;
    const float* bias = (z == 0) ? bias0 : (z == 1) ? bias1 : bias2;
    bf16* Ob = (z == 0) ? O0 : (z == 1) ? O1 : O2;

    int t = threadIdx.x, lane = t & 63, w = t >> 6, quad = lane >> 4, l15 = lane & 15;
    int row0 = blockIdx.y * 128 + (w >> 1) * 64;
    int col0 = blockIdx.x * 128 + (w & 1) * 64;
    f32x4 acc[4][4];
#pragma unroll
    for (int i = 0; i < 4; i++)
#pragma unroll
        for (int j = 0; j < 4; j++) acc[i][j] = (f32x4){0.f, 0.f, 0.f, 0.f};
    const bf16* Ap = A + (size_t)(row0 + l15) * 256 + quad * 8;
    const bf16* Bp = BT + (size_t)(col0 + l15) * 256 + quad * 8;
#pragma unroll
    for (int k = 0; k < 8; k++) {
        bf16x8 af[4], bfr[4];
#pragma unroll
        for (int mt = 0; mt < 4; mt++) af[mt] = *(const bf16x8*)(Ap + mt * 16 * 256 + k * 32);
#pragma unroll
        for (int nt = 0; nt < 4; nt++) bfr[nt] = *(const bf16x8*)(Bp + nt * 16 * 256 + k * 32);
#pragma unroll
        for (int mt = 0; mt < 4; mt++)
#pragma unroll
            for (int nt = 0; nt < 4; nt++)
                acc[mt][nt] = __builtin_amdgcn_mfma_f32_16x16x32_bf16(af[mt], bfr[nt], acc[mt][nt], 0, 0, 0);
    }
#pragma unroll
    for (int mt = 0; mt < 4; mt++)
#pragma unroll
        for (int nt = 0; nt < 4; nt++) {
            int rb = row0 + mt * 16 + quad * 4;
            int c = col0 + nt * 16 + l15;
            float bv = bias[c];
#pragma unroll
            for (int reg = 0; reg < 4; reg++)
                Ob[(size_t)(rb + reg) * 256 + c] = f2b(acc[mt][nt][reg] + bv);
        }
}

// ---------------------------------------------------------------- final GEMM (fp32 out + residual)
__global__ __launch_bounds__(256, 3) void gemm_out_kernel(
    const bf16* __restrict__ A, const bf16* __restrict__ BT,
    const float* __restrict__ bias, float* __restrict__ Of, const float* __restrict__ resid)
{
    int t = threadIdx.x, lane = t & 63, w = t >> 6, quad = lane >> 4, l15 = lane & 15;
    int row0 = blockIdx.y * 128 + (w >> 1) * 64;
    int col0 = blockIdx.x * 128 + (w & 1) * 64;
    f32x4 acc[4][4];
#pragma unroll
    for (int i = 0; i < 4; i++)
#pragma unroll
        for (int j = 0; j < 4; j++) acc[i][j] = (f32x4){0.f, 0.f, 0.f, 0.f};
    const bf16* Ap = A + (size_t)(row0 + l15) * 256 + quad * 8;
    const bf16* Bp = BT + (size_t)(col0 + l15) * 256 + quad * 8;
#pragma unroll
    for (int k = 0; k < 8; k++) {
        bf16x8 af[4], bfr[4];
#pragma unroll
        for (int mt = 0; mt < 4; mt++) af[mt] = *(const bf16x8*)(Ap + mt * 16 * 256 + k * 32);
#pragma unroll
        for (int nt = 0; nt < 4; nt++) bfr[nt] = *(const bf16x8*)(Bp + nt * 16 * 256 + k * 32);
#pragma unroll
        for (int mt = 0; mt < 4; mt++)
#pragma unroll
            for (int nt = 0; nt < 4; nt++)
                acc[mt][nt] = __builtin_amdgcn_mfma_f32_16x16x32_bf16(af[mt], bfr[nt], acc[mt][nt], 0, 0, 0);
    }
#pragma unroll
    for (int mt = 0; mt < 4; mt++)
#pragma unroll
        for (int nt = 0; nt < 4; nt++) {
            int rb = row0 + mt * 16 + quad * 4;
            int c = col0 + nt * 16 + l15;
            float bv = bias[c];
#pragma unroll
            for (int reg = 0; reg < 4; reg++) {
                int r = rb + reg;
                Of[(size_t)r * 256 + c] = acc[mt][nt][reg] + bv + resid[(size_t)r * 259 + 3 + c];
            }
        }
}

// ---------------------------------------------------------------- fused gram + top-16 KNN
// ROUND-19: fully independent waves -- zero LDS, zero barriers, zero
// divergent selection.
// Evidence chain: R0-R6 all show VALU-time ~58-80us / MFMA-time ~14us with
// duration 225-325us, insensitive to occupancy (R3), memory tier (R2), and
// intra-wave pipelining (R6: gram-before-selection failed because the
// data-dependent while+ballot selection blocks compiler scheduling). The
// structural loss = barrier lockstep + LDS round-trip + divergent selector.
// This version removes all three:
//  - each wave owns 16 rows; A-frags (8x bf16x8 = 32 VGPR) live in regs;
//  - stream cols in 32-chunks: 16 MFMAs; candidates come STRAIGHT from acc
//    (C-layout: lane q*16+c holds rows 4q..4q+3, cols c / c+16);
//  - branchless lane-local sorted top-16 per owned row (L[4][16] = 64 VGPR,
//    R5-proven ~27us chip VALU), fully schedulable against loads/MFMA;
//  - final merge per quad-group: 16 pop-mins via shfl_xor 1/2/4/8, the 4
//    groups merge their 4 rows concurrently; no block-wide sync anywhere.
// 256 blocks x 256 thr (4 waves), XCD batch pinning kept (xcd=g&7). The 4
// waves/block run identical branchless code over the same B stream ->
// natural L1 sharing of each 16KB chunk. launch_bounds(256,1): VGPR cap
// model 2048/(4 waves x 1) = 512, est ~190 used -> no spill.
// Tripwires: WRITE_SIZE ~1MB (idxout only), VGPR < 256.
__global__ __launch_bounds__(256, 1) void knn_kernel(
    const bf16* __restrict__ featb, const float* __restrict__ sq, int* __restrict__ idxout)
{
    int t = threadIdx.x, lane = t & 63, w = t >> 6, quad = lane >> 4, l15 = lane & 15;
    int g = blockIdx.x;
    int b = (g >> 1) & 3;                       // batch = xcd>>1  (xcd = g&7)
    int blk = ((g >> 3) << 1) | (g & 1);        // 0..63 within batch
    int row0 = blk * 64 + w * 16;
    const bf16* F = featb + (size_t)b * SS * 256;
    const float* sqb = sq + b * SS;

    // A fragments: 16 rows x 256 dims, resident for the whole kernel
    bf16x8 af[8];
    const bf16* Ap = F + (size_t)(row0 + l15) * 256 + quad * 8;
#pragma unroll
    for (int k = 0; k < 8; k++) af[k] = *(const bf16x8*)(Ap + k * 32);

    // lane-local sorted (ascending) top-16 for each of the 4 owned rows
    unsigned int L[4][16];
#pragma unroll
    for (int j = 0; j < 4; j++)
#pragma unroll
        for (int i = 0; i < 16; i++) L[j][i] = 0xFFFFFFFFu;

#pragma unroll 1
    for (int c0 = 0; c0 < SS; c0 += 32) {
        const bf16* Bp = F + (size_t)(c0 + l15) * 256 + quad * 8;
        bf16x8 b0[8], b1[8];
#pragma unroll
        for (int k = 0; k < 8; k++) {
            b0[k] = *(const bf16x8*)(Bp + k * 32);
            b1[k] = *(const bf16x8*)(Bp + 16 * 256 + k * 32);
        }
        f32x4 acc0 = (f32x4){0.f, 0.f, 0.f, 0.f};
        f32x4 acc1 = (f32x4){0.f, 0.f, 0.f, 0.f};
#pragma unroll
        for (int k = 0; k < 8; k++) {
            acc0 = __builtin_amdgcn_mfma_f32_16x16x32_bf16(af[k], b0[k], acc0, 0, 0, 0);
            acc1 = __builtin_amdgcn_mfma_f32_16x16x32_bf16(af[k], b1[k], acc1, 0, 0, 0);
        }
        float sq0 = sqb[c0 + l15];
        float sq1 = sqb[c0 + 16 + l15];
        // fold 8 candidates (4 rows x 2 col-halves) into the private lists
#pragma unroll
        for (int j = 0; j < 4; j++) {
            {
                float d = fmaf(-2.0f, acc0[j], sq0);
                unsigned int bits = __float_as_uint(d);
                unsigned int key = bits ^ ((unsigned int)(((int)bits) >> 31) | 0x80000000u);
                unsigned int val = (key & 0xFFFFF000u) | (unsigned int)(c0 + l15);
#pragma unroll
                for (int i = 0; i < 16; i++) {
                    unsigned int lo = min(L[j][i], val);
                    val = max(L[j][i], val);
                    L[j][i] = lo;
                }
            }
            {
                float d = fmaf(-2.0f, acc1[j], sq1);
                unsigned int bits = __float_as_uint(d);
                unsigned int key = bits ^ ((unsigned int)(((int)bits) >> 31) | 0x80000000u);
                unsigned int val = (key & 0xFFFFF000u) | (unsigned int)(c0 + 16 + l15);
#pragma unroll
                for (int i = 0; i < 16; i++) {
                    unsigned int lo = min(L[j][i], val);
                    val = max(L[j][i], val);
                    L[j][i] = lo;
                }
            }
        }
    }

    // merge: each quad-group (16 lanes) merges its 4 rows; 16 pop-mins.
    // keys are unique (low 12 bits = col), so the winner lane is unique.
    unsigned int outv[4] = {0u, 0u, 0u, 0u};
#pragma unroll 1
    for (int k = 0; k < 16; k++) {
#pragma unroll
        for (int j = 0; j < 4; j++) {
            unsigned int m = L[j][0];
#pragma unroll
            for (int off = 1; off <= 8; off <<= 1)
                m = min(m, (unsigned int)__shfl_xor((int)m, off));
            unsigned long long msk = __ballot(L[j][0] == m);
            unsigned int part = (unsigned int)((msk >> (quad * 16)) & 0xFFFFull);
            int wl = __ffs(part) - 1;
            bool win = (l15 == wl);
#pragma unroll
            for (int i = 0; i < 15; i++) L[j][i] = win ? L[j][i + 1] : L[j][i];
            L[j][15] = win ? 0xFFFFFFFFu : L[j][15];
            outv[j] = (l15 == k) ? m : outv[j];
        }
    }
#pragma unroll
    for (int j = 0; j < 4; j++)
        idxout[((size_t)b * SS + row0 + quad * 4 + j) * 16 + l15] = (int)(outv[j] & 0xFFFu);
}

// ---------------------------------------------------------------- fused edge MLP
// ROUND-11 config (best): 512 threads (8 waves), 8 groups/block, per-wave
// 32-col g2T slice (bg[2][8] = 64 VGPRs), 16 waves/CU.
__global__ __launch_bounds__(512, 3) void edge_kernel(
    const bf16* __restrict__ qb, const bf16* __restrict__ kg1, const bf16* __restrict__ vf,
    const bf16* __restrict__ g2T, const float* __restrict__ g2b,
    const int* __restrict__ idx, bf16* __restrict__ res)
{
    __shared__ __align__(16) bf16 e1[8 * 16 * 264];
    __shared__ int nbrs[8][16];
    int t = threadIdx.x, lane = t & 63, w = t >> 6, quad = lane >> 4, l15 = lane & 15;
    int G0 = blockIdx.x * 8;
    int bb = G0 & ~(SS - 1);
    if (t < 128) {
        int g = t >> 4, r = t & 15;
        nbrs[g][r] = bb + idx[(size_t)(G0 + g) * 16 + r];
    }
    bf16x8 bg[2][8];
#pragma unroll
    for (int nt = 0; nt < 2; nt++)
#pragma unroll
        for (int k = 0; k < 8; k++)
            bg[nt][k] = *(const bf16x8*)(g2T + (size_t)(w * 32 + nt * 16 + l15) * 256 + k * 32 + quad * 8);
    __syncthreads();
#pragma unroll 4
    for (int i = 0; i < 8; i++) {
        int f = i * 512 + t;
        int c8 = f & 31, r = (f >> 5) & 15, g = f >> 9;
        int nbr = nbrs[g][r];
        bf16x8 qv = *(const bf16x8*)(qb + (size_t)(G0 + g) * 256 + c8 * 8);
        bf16x8 kv = *(const bf16x8*)(kg1 + (size_t)nbr * 256 + c8 * 8);
        bf16x8 e;
#pragma unroll
        for (int j = 0; j < 8; j++) {
            float d = b2f(qv[j]) - b2f(kv[j]);
            e[j] = f2b(fmaxf(d, 0.0f));
        }
        *(bf16x8*)(&e1[(g * 16 + r) * 264 + c8 * 8]) = e;
    }
    __syncthreads();
#pragma unroll 1
    for (int g = 0; g < 8; g++) {
        f32x4 acc[2];
#pragma unroll
        for (int nt = 0; nt < 2; nt++) acc[nt] = (f32x4){0.f, 0.f, 0.f, 0.f};
#pragma unroll
        for (int k = 0; k < 8; k++) {
            bf16x8 a = *(const bf16x8*)(&e1[(g * 16 + l15) * 264 + k * 32 + quad * 8]);
#pragma unroll
            for (int nt = 0; nt < 2; nt++)
                acc[nt] = __builtin_amdgcn_mfma_f32_16x16x32_bf16(a, bg[nt][k], acc[nt], 0, 0, 0);
        }
        int grow = G0 + g;
#pragma unroll
        for (int nt = 0; nt < 2; nt++) {
            int col = w * 32 + nt * 16 + l15;
            float b2v = g2b[col];
            float lg[4], p[4];
#pragma unroll
            for (int reg = 0; reg < 4; reg++) lg[reg] = (acc[nt][reg] + b2v) * 0.0625f;
            float mx = fmaxf(fmaxf(lg[0], lg[1]), fmaxf(lg[2], lg[3]));
            mx = fmaxf(mx, __shfl_xor(mx, 16));
            mx = fmaxf(mx, __shfl_xor(mx, 32));
            float ps = 0.f;
#pragma unroll
            for (int reg = 0; reg < 4; reg++) { p[reg] = __expf(lg[reg] - mx); ps += p[reg]; }
            ps += __shfl_xor(ps, 16);
            ps += __shfl_xor(ps, 32);
            float inv = __builtin_amdgcn_rcpf(ps);
            float rs = 0.f;
#pragma unroll
            for (int reg = 0; reg < 4; reg++) {
                int nbr = nbrs[g][quad * 4 + reg];
                rs += p[reg] * b2f(vf[(size_t)nbr * 256 + col]);
            }
            rs *= inv;
            rs += __shfl_xor(rs, 16);
            rs += __shfl_xor(rs, 32);
            if (quad == 0) res[(size_t)grow * 256 + col] = f2b(rs);
        }
    }
}

// ---------------------------------------------------------------- launcher
extern "C" void kernel_launch(void* const* d_in, const int* in_sizes, int n_in,
                              void* d_out, int out_size, void* d_ws, size_t ws_size,
                              hipStream_t stream)
{
    (void)in_sizes; (void)n_in; (void)out_size; (void)ws_size;
    const float* x    = (const float*)d_in[0];
    const float* fc1w = (const float*)d_in[1];
    const float* fc1b = (const float*)d_in[2];
    const float* fc2w = (const float*)d_in[3];
    const float* fc2b = (const float*)d_in[4];
    const float* wqw  = (const float*)d_in[5];
    const float* wkw  = (const float*)d_in[6];
    const float* wvw  = (const float*)d_in[7];
    const float* g1w  = (const float*)d_in[8];
    const float* g1b  = (const float*)d_in[9];
    const float* g2w  = (const float*)d_in[10];
    const float* g2b  = (const float*)d_in[11];

    float* pos_out = (float*)d_out;
    float* out     = (float*)d_out + (size_t)NROWS * 3;

    char* ws = (char*)d_ws;
    size_t off = 0;
    auto alloc = [&](size_t bytes) { void* p = ws + off; off += (bytes + 255) & ~(size_t)255; return p; };
    bf16* featb = (bf16*)alloc((size_t)NROWS * 256 * 2);
    bf16* qbuf  = (bf16*)alloc((size_t)NROWS * 256 * 2);
    bf16* kg    = (bf16*)alloc((size_t)NROWS * 256 * 2);
    bf16* vf    = (bf16*)alloc((size_t)NROWS * 256 * 2);
    bf16* res   = (bf16*)alloc((size_t)NROWS * 256 * 2);
    float* sq   = (float*)alloc((size_t)NROWS * 4);
    int* idx    = (int*)alloc((size_t)NROWS * 16 * 4);
    float* M1q  = (float*)alloc(65536 * 4);
    float* M1k  = (float*)alloc(65536 * 4);
    bf16* WqT   = (bf16*)alloc(65536 * 2);
    bf16* WkT   = (bf16*)alloc(65536 * 2);
    bf16* WvT   = (bf16*)alloc(65536 * 2);
    bf16* fc2T  = (bf16*)alloc(65536 * 2);
    bf16* g2T   = (bf16*)alloc(65536 * 2);
    float* qbias = (float*)alloc(256 * 4);
    float* kbias = (float*)alloc(256 * 4);
    float* vbias = (float*)alloc(256 * 4);

    prep_kernel<<<NROWS, 256, 0, stream>>>(x, pos_out, featb, sq);
    wprep1_kernel<<<dim3(256, 4), 256, 0, stream>>>(wqw, wkw, g1w, fc2w, g2w, M1q, M1k, fc2T, g2T);
    wprep2_kernel<<<dim3(256, 4), 256, 0, stream>>>(fc1w, fc1b, M1q, M1k, wvw, g1b,
                                                    WqT, WkT, WvT, qbias, kbias, vbias);

    qkv_gemm_kernel<<<dim3(2, NROWS / 128, 3), 256, 0, stream>>>(
        featb, WqT, WkT, WvT, qbias, kbias, vbias, qbuf, kg, vf);

    knn_kernel<<<256, 256, 0, stream>>>(featb, sq, idx);

    edge_kernel<<<NROWS / 8, 512, 0, stream>>>(qbuf, kg, vf, g2T, g2b, idx, res);

    gemm_out_kernel<<<dim3(2, NROWS / 128), 256, 0, stream>>>(res, fc2T, fc2b, out, x);
}

// Round 8
// 533.746 us; speedup vs baseline: 1.1303x; 1.1303x over previous
//
#include <hip/hip_runtime.h>

#define SS 4096
#define NROWS 16384   // B*S

typedef __bf16 bf16;
typedef __attribute__((ext_vector_type(8))) __bf16 bf16x8;
typedef __attribute__((ext_vector_type(4))) float f32x4;

__device__ __forceinline__ float b2f(bf16 v) { return (float)v; }
__device__ __forceinline__ bf16  f2b(float f) { return (bf16)f; }

// ---------------------------------------------------------------- prep
__global__ __launch_bounds__(256) void prep_kernel(
    const float* __restrict__ x, float* __restrict__ pos,
    bf16* __restrict__ featb, float* __restrict__ sq)
{
    int row = blockIdx.x, t = threadIdx.x;
    const float* xr = x + (size_t)row * 259;
    float v = xr[3 + t];
    featb[(size_t)row * 256 + t] = f2b(v);
    if (t < 3) pos[row * 3 + t] = xr[t];
    float s = v * v;
#pragma unroll
    for (int o = 32; o >= 1; o >>= 1) s += __shfl_xor(s, o);
    __shared__ float wsum[4];
    if ((t & 63) == 0) wsum[t >> 6] = s;
    __syncthreads();
    if (t == 0) sq[row] = wsum[0] + wsum[1] + wsum[2] + wsum[3];
}

// ---------------------------------------------------------------- weight prep, stage 1
__global__ void wprep1_kernel(const float* __restrict__ wqw, const float* __restrict__ wkw,
                              const float* __restrict__ g1w, const float* __restrict__ fc2w,
                              const float* __restrict__ g2w,
                              float* __restrict__ M1q, float* __restrict__ M1k,
                              bf16* __restrict__ fc2T, bf16* __restrict__ g2T)
{
    int job = blockIdx.y, i = blockIdx.x, j = threadIdx.x;
    if (job < 2) {
        const float* A = job ? wkw : wqw;
        float acc = 0.f;
#pragma unroll 4
        for (int d = 0; d < 256; d++) acc += A[i * 256 + d] * g1w[d * 256 + j];
        (job ? M1k : M1q)[i * 256 + j] = acc;
    } else {
        const float* S = (job == 2) ? fc2w : g2w;
        bf16* D = (job == 2) ? fc2T : g2T;
        D[i * 256 + j] = f2b(S[j * 256 + i]);
    }
}

// ---------------------------------------------------------------- weight prep, stage 2
__global__ void wprep2_kernel(const float* __restrict__ fc1w, const float* __restrict__ fc1b,
                              const float* __restrict__ M1q, const float* __restrict__ M1k,
                              const float* __restrict__ wvw, const float* __restrict__ g1b,
                              bf16* __restrict__ WqT, bf16* __restrict__ WkT, bf16* __restrict__ WvT,
                              float* __restrict__ qbias, float* __restrict__ kbias, float* __restrict__ vbias)
{
    int job = blockIdx.y, n = blockIdx.x, k = threadIdx.x;
    if (job < 3) {
        const float* M = (job == 0) ? M1q : (job == 1) ? M1k : wvw;
        float acc = 0.f;
#pragma unroll 4
        for (int d = 0; d < 256; d++) acc += fc1w[k * 256 + d] * M[d * 256 + n];
        bf16* D = (job == 0) ? WqT : (job == 1) ? WkT : WvT;
        D[n * 256 + k] = f2b(acc);
    } else if (n == 0) {
        float aq = 0.f, ak = 0.f, av = 0.f;
#pragma unroll 4
        for (int d = 0; d < 256; d++) {
            float f = fc1b[d];
            aq += f * M1q[d * 256 + k];
            ak += f * M1k[d * 256 + k];
            av += f * wvw[d * 256 + k];
        }
        qbias[k] = aq + g1b[k];
        kbias[k] = ak;
        vbias[k] = av;
    }
}

// ---------------------------------------------------------------- q/k/v GEMM (one launch, z-indexed)
__global__ __launch_bounds__(256, 3) void qkv_gemm_kernel(
    const bf16* __restrict__ A,
    const bf16* __restrict__ BT0, const bf16* __restrict__ BT1, const bf16* __restrict__ BT2,
    const float* __restrict__ bias0, const float* __restrict__ bias1, const float* __restrict__ bias2,
    bf16* __restrict__ O0, bf16* __restrict__ O1, bf16* __restrict__ O2)
{
    int z = blockIdx.z;
    const bf16* BT = (z == 0) ? BT0 : (z == 1) ? BT1 : BT2;
    const float* bias = (z == 0) ? bias0 : (z == 1) ? bias1 : bias2;
    bf16* Ob = (z == 0) ? O0 : (z == 1) ? O1 : O2;

    int t = threadIdx.x, lane = t & 63, w = t >> 6, quad = lane >> 4, l15 = lane & 15;
    int row0 = blockIdx.y * 128 + (w >> 1) * 64;
    int col0 = blockIdx.x * 128 + (w & 1) * 64;
    f32x4 acc[4][4];
#pragma unroll
    for (int i = 0; i < 4; i++)
#pragma unroll
        for (int j = 0; j < 4; j++) acc[i][j] = (f32x4){0.f, 0.f, 0.f, 0.f};
    const bf16* Ap = A + (size_t)(row0 + l15) * 256 + quad * 8;
    const bf16* Bp = BT + (size_t)(col0 + l15) * 256 + quad * 8;
#pragma unroll
    for (int k = 0; k < 8; k++) {
        bf16x8 af[4], bfr[4];
#pragma unroll
        for (int mt = 0; mt < 4; mt++) af[mt] = *(const bf16x8*)(Ap + mt * 16 * 256 + k * 32);
#pragma unroll
        for (int nt = 0; nt < 4; nt++) bfr[nt] = *(const bf16x8*)(Bp + nt * 16 * 256 + k * 32);
#pragma unroll
        for (int mt = 0; mt < 4; mt++)
#pragma unroll
            for (int nt = 0; nt < 4; nt++)
                acc[mt][nt] = __builtin_amdgcn_mfma_f32_16x16x32_bf16(af[mt], bfr[nt], acc[mt][nt], 0, 0, 0);
    }
#pragma unroll
    for (int mt = 0; mt < 4; mt++)
#pragma unroll
        for (int nt = 0; nt < 4; nt++) {
            int rb = row0 + mt * 16 + quad * 4;
            int c = col0 + nt * 16 + l15;
            float bv = bias[c];
#pragma unroll
            for (int reg = 0; reg < 4; reg++)
                Ob[(size_t)(rb + reg) * 256 + c] = f2b(acc[mt][nt][reg] + bv);
        }
}

// ---------------------------------------------------------------- final GEMM (fp32 out + residual)
__global__ __launch_bounds__(256, 3) void gemm_out_kernel(
    const bf16* __restrict__ A, const bf16* __restrict__ BT,
    const float* __restrict__ bias, float* __restrict__ Of, const float* __restrict__ resid)
{
    int t = threadIdx.x, lane = t & 63, w = t >> 6, quad = lane >> 4, l15 = lane & 15;
    int row0 = blockIdx.y * 128 + (w >> 1) * 64;
    int col0 = blockIdx.x * 128 + (w & 1) * 64;
    f32x4 acc[4][4];
#pragma unroll
    for (int i = 0; i < 4; i++)
#pragma unroll
        for (int j = 0; j < 4; j++) acc[i][j] = (f32x4){0.f, 0.f, 0.f, 0.f};
    const bf16* Ap = A + (size_t)(row0 + l15) * 256 + quad * 8;
    const bf16* Bp = BT + (size_t)(col0 + l15) * 256 + quad * 8;
#pragma unroll
    for (int k = 0; k < 8; k++) {
        bf16x8 af[4], bfr[4];
#pragma unroll
        for (int mt = 0; mt < 4; mt++) af[mt] = *(const bf16x8*)(Ap + mt * 16 * 256 + k * 32);
#pragma unroll
        for (int nt = 0; nt < 4; nt++) bfr[nt] = *(const bf16x8*)(Bp + nt * 16 * 256 + k * 32);
#pragma unroll
        for (int mt = 0; mt < 4; mt++)
#pragma unroll
            for (int nt = 0; nt < 4; nt++)
                acc[mt][nt] = __builtin_amdgcn_mfma_f32_16x16x32_bf16(af[mt], bfr[nt], acc[mt][nt], 0, 0, 0);
    }
#pragma unroll
    for (int mt = 0; mt < 4; mt++)
#pragma unroll
        for (int nt = 0; nt < 4; nt++) {
            int rb = row0 + mt * 16 + quad * 4;
            int c = col0 + nt * 16 + l15;
            float bv = bias[c];
#pragma unroll
            for (int reg = 0; reg < 4; reg++) {
                int r = rb + reg;
                Of[(size_t)r * 256 + c] = acc[mt][nt][reg] + bv + resid[(size_t)r * 259 + 3 + c];
            }
        }
}

// ---------------------------------------------------------------- fused gram + top-16 KNN
// ROUND-20: R7's algorithm (verified correct) with geometry fixed.
// R7 failure analysis: VGPR_Count=68 forced L[4][16]+af+b into AGPRs
// (accvgpr moves inflated VALU ~3x) AND 256 blocks x 4 waves = 1 wave/SIMD
// (zero TLP, all latency exposed) -> 345us.
// Fix, keeping the verified lane-local-list + quad-pop-merge machinery:
//  - 16 rows/block, 8 waves x 32-col slices, 1024 blocks, XCD-pinned;
//  - per lane: af[8]=32 VGPR, L[4][8]=32 VGPR (depth 8: per-row slice
//    top-16 spreads over 16 lanes; P(lane needs >8) ~1e-9 random data);
//    streamed b-frags; total ~110 VGPR -> fits 128, NO AGPR pressure;
//  - launch_bounds(512,2): 2 blocks/CU, 16 waves/CU, 4 waves/SIMD TLP;
//  - stream loop: 16 tiles x {16 loads, 16 MFMAs, 8 cand x 16-op ladder},
//    no barriers, 8 independent dep chains;
//  - merge: quad-pop (R7 pattern) -> per-wave top-16/row -> 8KB LDS ->
//    one barrier -> per-row 128-entry cross-wave pop-16 (wave w: rows 2w,2w+1).
// Cost model: VALU ~18us chip, MFMA ~28us, L2 traffic 1024x2MB = 256MB/XCD
// ~60us floor (overlapped). Tripwires: VGPR<128, WRITE_SIZE ~1MB.
__global__ __launch_bounds__(512, 2) void knn_kernel(
    const bf16* __restrict__ featb, const float* __restrict__ sq, int* __restrict__ idxout)
{
    __shared__ unsigned int mbuf[16 * 8 * 16];   // [row][wave][slot] = 8KB
    int t = threadIdx.x, lane = t & 63, w = t >> 6, quad = lane >> 4, l15 = lane & 15;
    int g = blockIdx.x;
    int b = (g >> 1) & 3;                       // batch = xcd>>1  (xcd = g&7)
    int rowblock = ((g >> 3) << 1) | (g & 1);   // 0..255 within batch
    int row0 = rowblock * 16;
    const bf16* F = featb + (size_t)b * SS * 256;
    const float* sqb = sq + b * SS;

    // A fragments: 16 rows x 256 dims, resident all kernel (32 VGPR)
    bf16x8 af[8];
    const bf16* Ap = F + (size_t)(row0 + l15) * 256 + quad * 8;
#pragma unroll
    for (int k = 0; k < 8; k++) af[k] = *(const bf16x8*)(Ap + k * 32);

    // lane-local sorted (ascending) top-8 for each of the 4 owned row-slots
    unsigned int L[4][8];
#pragma unroll
    for (int j = 0; j < 4; j++)
#pragma unroll
        for (int i = 0; i < 8; i++) L[j][i] = 0xFFFFFFFFu;

#pragma unroll 1
    for (int tile = 0; tile < 16; tile++) {
        int c0 = tile * 256 + w * 32;           // this wave's 32-col slice
        const bf16* Bp = F + (size_t)(c0 + l15) * 256 + quad * 8;
        f32x4 acc0 = (f32x4){0.f, 0.f, 0.f, 0.f};
        f32x4 acc1 = (f32x4){0.f, 0.f, 0.f, 0.f};
#pragma unroll
        for (int k = 0; k < 8; k++) {
            bf16x8 b0 = *(const bf16x8*)(Bp + k * 32);
            bf16x8 b1 = *(const bf16x8*)(Bp + 16 * 256 + k * 32);
            acc0 = __builtin_amdgcn_mfma_f32_16x16x32_bf16(af[k], b0, acc0, 0, 0, 0);
            acc1 = __builtin_amdgcn_mfma_f32_16x16x32_bf16(af[k], b1, acc1, 0, 0, 0);
        }
        float sq0 = sqb[c0 + l15];
        float sq1 = sqb[c0 + 16 + l15];
        // fold 8 candidates: acc0[j] -> (row quad*4+j, col c0+l15),
        //                    acc1[j] -> (row quad*4+j, col c0+16+l15)
#pragma unroll
        for (int j = 0; j < 4; j++) {
            {
                float d = fmaf(-2.0f, acc0[j], sq0);
                unsigned int bits = __float_as_uint(d);
                unsigned int key = bits ^ ((unsigned int)(((int)bits) >> 31) | 0x80000000u);
                unsigned int val = (key & 0xFFFFF000u) | (unsigned int)(c0 + l15);
#pragma unroll
                for (int i = 0; i < 8; i++) {
                    unsigned int lo = min(L[j][i], val);
                    val = max(L[j][i], val);
                    L[j][i] = lo;
                }
            }
            {
                float d = fmaf(-2.0f, acc1[j], sq1);
                unsigned int bits = __float_as_uint(d);
                unsigned int key = bits ^ ((unsigned int)(((int)bits) >> 31) | 0x80000000u);
                unsigned int val = (key & 0xFFFFF000u) | (unsigned int)(c0 + 16 + l15);
#pragma unroll
                for (int i = 0; i < 8; i++) {
                    unsigned int lo = min(L[j][i], val);
                    val = max(L[j][i], val);
                    L[j][i] = lo;
                }
            }
        }
    }

    // stage 1: quad-pop merge (R7-verified pattern). Row quad*4+j is held by
    // the 16 lanes of this quad; pop the 16 smallest of their 16x8 pool.
    unsigned int wout[4];
#pragma unroll
    for (int j = 0; j < 4; j++) wout[j] = 0u;
#pragma unroll 1
    for (int k = 0; k < 16; k++) {
#pragma unroll
        for (int j = 0; j < 4; j++) {
            unsigned int m = L[j][0];
#pragma unroll
            for (int off = 1; off <= 8; off <<= 1)
                m = min(m, (unsigned int)__shfl_xor((int)m, off));
            unsigned long long msk = __ballot(L[j][0] == m);
            unsigned int part = (unsigned int)((msk >> (quad * 16)) & 0xFFFFull);
            int wl = __ffs(part) - 1;
            bool win = (l15 == wl);
#pragma unroll
            for (int i = 0; i < 7; i++) L[j][i] = win ? L[j][i + 1] : L[j][i];
            L[j][7] = win ? 0xFFFFFFFFu : L[j][7];
            wout[j] = (l15 == k) ? m : wout[j];
        }
    }
    // write per-wave top-16 per row: mbuf[row][w][slot]
#pragma unroll
    for (int j = 0; j < 4; j++)
        mbuf[(quad * 4 + j) * 128 + w * 16 + l15] = wout[j];
    __syncthreads();

    // stage 2: wave w merges rows 2w and 2w+1 (128 entries each)
#pragma unroll 1
    for (int rr = w * 2; rr < w * 2 + 2; rr++) {
        unsigned int e0 = mbuf[rr * 128 + lane];
        unsigned int e1 = mbuf[rr * 128 + 64 + lane];
        unsigned int lo = min(e0, e1), hi = max(e0, e1);
        unsigned int res = 0u;
#pragma unroll 1
        for (int k = 0; k < 16; k++) {
            unsigned int m = lo;
#pragma unroll
            for (int off = 1; off <= 32; off <<= 1)
                m = min(m, (unsigned int)__shfl_xor((int)m, off));
            unsigned long long msk = __ballot(lo == m);
            int wl = __ffsll((long long)msk) - 1;
            bool win = (lane == wl);
            lo = win ? hi : lo;
            hi = win ? 0xFFFFFFFFu : hi;
            res = (lane == k) ? m : res;
        }
        if (lane < 16)
            idxout[((size_t)b * SS + row0 + rr) * 16 + lane] = (int)(res & 0xFFFu);
    }
}

// ---------------------------------------------------------------- fused edge MLP
// ROUND-11 config (best): 512 threads (8 waves), 8 groups/block, per-wave
// 32-col g2T slice (bg[2][8] = 64 VGPRs), 16 waves/CU.
__global__ __launch_bounds__(512, 3) void edge_kernel(
    const bf16* __restrict__ qb, const bf16* __restrict__ kg1, const bf16* __restrict__ vf,
    const bf16* __restrict__ g2T, const float* __restrict__ g2b,
    const int* __restrict__ idx, bf16* __restrict__ res)
{
    __shared__ __align__(16) bf16 e1[8 * 16 * 264];
    __shared__ int nbrs[8][16];
    int t = threadIdx.x, lane = t & 63, w = t >> 6, quad = lane >> 4, l15 = lane & 15;
    int G0 = blockIdx.x * 8;
    int bb = G0 & ~(SS - 1);
    if (t < 128) {
        int g = t >> 4, r = t & 15;
        nbrs[g][r] = bb + idx[(size_t)(G0 + g) * 16 + r];
    }
    bf16x8 bg[2][8];
#pragma unroll
    for (int nt = 0; nt < 2; nt++)
#pragma unroll
        for (int k = 0; k < 8; k++)
            bg[nt][k] = *(const bf16x8*)(g2T + (size_t)(w * 32 + nt * 16 + l15) * 256 + k * 32 + quad * 8);
    __syncthreads();
#pragma unroll 4
    for (int i = 0; i < 8; i++) {
        int f = i * 512 + t;
        int c8 = f & 31, r = (f >> 5) & 15, g = f >> 9;
        int nbr = nbrs[g][r];
        bf16x8 qv = *(const bf16x8*)(qb + (size_t)(G0 + g) * 256 + c8 * 8);
        bf16x8 kv = *(const bf16x8*)(kg1 + (size_t)nbr * 256 + c8 * 8);
        bf16x8 e;
#pragma unroll
        for (int j = 0; j < 8; j++) {
            float d = b2f(qv[j]) - b2f(kv[j]);
            e[j] = f2b(fmaxf(d, 0.0f));
        }
        *(bf16x8*)(&e1[(g * 16 + r) * 264 + c8 * 8]) = e;
    }
    __syncthreads();
#pragma unroll 1
    for (int g = 0; g < 8; g++) {
        f32x4 acc[2];
#pragma unroll
        for (int nt = 0; nt < 2; nt++) acc[nt] = (f32x4){0.f, 0.f, 0.f, 0.f};
#pragma unroll
        for (int k = 0; k < 8; k++) {
            bf16x8 a = *(const bf16x8*)(&e1[(g * 16 + l15) * 264 + k * 32 + quad * 8]);
#pragma unroll
            for (int nt = 0; nt < 2; nt++)
                acc[nt] = __builtin_amdgcn_mfma_f32_16x16x32_bf16(a, bg[nt][k], acc[nt], 0, 0, 0);
        }
        int grow = G0 + g;
#pragma unroll
        for (int nt = 0; nt < 2; nt++) {
            int col = w * 32 + nt * 16 + l15;
            float b2v = g2b[col];
            float lg[4], p[4];
#pragma unroll
            for (int reg = 0; reg < 4; reg++) lg[reg] = (acc[nt][reg] + b2v) * 0.0625f;
            float mx = fmaxf(fmaxf(lg[0], lg[1]), fmaxf(lg[2], lg[3]));
            mx = fmaxf(mx, __shfl_xor(mx, 16));
            mx = fmaxf(mx, __shfl_xor(mx, 32));
            float ps = 0.f;
#pragma unroll
            for (int reg = 0; reg < 4; reg++) { p[reg] = __expf(lg[reg] - mx); ps += p[reg]; }
            ps += __shfl_xor(ps, 16);
            ps += __shfl_xor(ps, 32);
            float inv = __builtin_amdgcn_rcpf(ps);
            float rs = 0.f;
#pragma unroll
            for (int reg = 0; reg < 4; reg++) {
                int nbr = nbrs[g][quad * 4 + reg];
                rs += p[reg] * b2f(vf[(size_t)nbr * 256 + col]);
            }
            rs *= inv;
            rs += __shfl_xor(rs, 16);
            rs += __shfl_xor(rs, 32);
            if (quad == 0) res[(size_t)grow * 256 + col] = f2b(rs);
        }
    }
}

// ---------------------------------------------------------------- launcher
extern "C" void kernel_launch(void* const* d_in, const int* in_sizes, int n_in,
                              void* d_out, int out_size, void* d_ws, size_t ws_size,
                              hipStream_t stream)
{
    (void)in_sizes; (void)n_in; (void)out_size; (void)ws_size;
    const float* x    = (const float*)d_in[0];
    const float* fc1w = (const float*)d_in[1];
    const float* fc1b = (const float*)d_in[2];
    const float* fc2w = (const float*)d_in[3];
    const float* fc2b = (const float*)d_in[4];
    const float* wqw  = (const float*)d_in[5];
    const float* wkw  = (const float*)d_in[6];
    const float* wvw  = (const float*)d_in[7];
    const float* g1w  = (const float*)d_in[8];
    const float* g1b  = (const float*)d_in[9];
    const float* g2w  = (const float*)d_in[10];
    const float* g2b  = (const float*)d_in[11];

    float* pos_out = (float*)d_out;
    float* out     = (float*)d_out + (size_t)NROWS * 3;

    char* ws = (char*)d_ws;
    size_t off = 0;
    auto alloc = [&](size_t bytes) { void* p = ws + off; off += (bytes + 255) & ~(size_t)255; return p; };
    bf16* featb = (bf16*)alloc((size_t)NROWS * 256 * 2);
    bf16* qbuf  = (bf16*)alloc((size_t)NROWS * 256 * 2);
    bf16* kg    = (bf16*)alloc((size_t)NROWS * 256 * 2);
    bf16* vf    = (bf16*)alloc((size_t)NROWS * 256 * 2);
    bf16* res   = (bf16*)alloc((size_t)NROWS * 256 * 2);
    float* sq   = (float*)alloc((size_t)NROWS * 4);
    int* idx    = (int*)alloc((size_t)NROWS * 16 * 4);
    float* M1q  = (float*)alloc(65536 * 4);
    float* M1k  = (float*)alloc(65536 * 4);
    bf16* WqT   = (bf16*)alloc(65536 * 2);
    bf16* WkT   = (bf16*)alloc(65536 * 2);
    bf16* WvT   = (bf16*)alloc(65536 * 2);
    bf16* fc2T  = (bf16*)alloc(65536 * 2);
    bf16* g2T   = (bf16*)alloc(65536 * 2);
    float* qbias = (float*)alloc(256 * 4);
    float* kbias = (float*)alloc(256 * 4);
    float* vbias = (float*)alloc(256 * 4);

    prep_kernel<<<NROWS, 256, 0, stream>>>(x, pos_out, featb, sq);
    wprep1_kernel<<<dim3(256, 4), 256, 0, stream>>>(wqw, wkw, g1w, fc2w, g2w, M1q, M1k, fc2T, g2T);
    wprep2_kernel<<<dim3(256, 4), 256, 0, stream>>>(fc1w, fc1b, M1q, M1k, wvw, g1b,
                                                    WqT, WkT, WvT, qbias, kbias, vbias);

    qkv_gemm_kernel<<<dim3(2, NROWS / 128, 3), 256, 0, stream>>>(
        featb, WqT, WkT, WvT, qbias, kbias, vbias, qbuf, kg, vf);

    knn_kernel<<<1024, 512, 0, stream>>>(featb, sq, idx);

    edge_kernel<<<NROWS / 8, 512, 0, stream>>>(qbuf, kg, vf, g2T, g2b, idx, res);

    gemm_out_kernel<<<dim3(2, NROWS / 128), 256, 0, stream>>>(res, fc2T, fc2b, out, x);
}